// Round 2
// baseline (236.919 us; speedup 1.0000x reference)
//
#include <hip/hip_runtime.h>

// GroupSort: x[32,256,64,64] fp32. For each channel pair (2k, 2k+1):
//   d = x[2k] - x[2k+1]; r = relu(d); out[2k] = x[2k] - r; out[2k+1] = x[2k+1] + r
// Pure streaming elementwise op: 128 MiB in + 128 MiB out, zero reuse.
//
// R1 (coalescing fix): each load/store instruction is a contiguous
//   64-lane x 16 B = 1 KiB wave transaction. Gained 6.4 us -> partial-line
//   transactions were NOT the dominant cost.
// R2 (this round):
//   - PLAIN cached loads (nt only on stores). The 6.29 TB/s copy ubench
//     (m13) uses plain loads; nt-loads demote requests with zero upside
//     for a stream that touches each line exactly once.
//   - 2x memory-level parallelism: 8 loads (128 B) in flight per thread
//     before the vmcnt wait, then 8 stores. Halves thread count (1M) and
//     per-thread address setup; deeper read bursts before the read->write
//     bus turnaround.
//
// Layout: plane = H*W = 4096 floats = 1024 float4. Pair stride = 2 planes.
// 256 threads per plane-pair; thread owns slots within + {0,256,512,768}
// of the even plane and the same slots +1024 of the odd plane.

typedef float f32x4 __attribute__((ext_vector_type(4)));

__device__ __forceinline__ void nt_store4(f32x4* p, f32x4 v) {
    __builtin_nontemporal_store(v, p);
}

__device__ __forceinline__ void pair_op(const f32x4 a, const f32x4 b,
                                        f32x4& lo, f32x4& hi) {
#pragma unroll
    for (int i = 0; i < 4; ++i) {
        float d = a[i] - b[i];
        float r = d > 0.0f ? d : 0.0f;
        lo[i] = a[i] - r;
        hi[i] = b[i] + r;
    }
}

__global__ __launch_bounds__(256) void groupsort_kernel(
    const f32x4* __restrict__ x, f32x4* __restrict__ out) {
    const long t = (long)blockIdx.x * blockDim.x + threadIdx.x;
    const long pair   = t >> 8;          // 256 threads per plane-pair
    const long within = t & 255;         // contiguous across the wave
    const long base = pair * 2048 + within;

    // even plane slots: base + k*256 (k=0..3); odd plane: +1024 float4
    f32x4 a[4], b[4];
#pragma unroll
    for (int k = 0; k < 4; ++k) a[k] = x[base + k * 256];
#pragma unroll
    for (int k = 0; k < 4; ++k) b[k] = x[base + k * 256 + 1024];

    f32x4 lo[4], hi[4];
#pragma unroll
    for (int k = 0; k < 4; ++k) pair_op(a[k], b[k], lo[k], hi[k]);

#pragma unroll
    for (int k = 0; k < 4; ++k) nt_store4(out + base + k * 256, lo[k]);
#pragma unroll
    for (int k = 0; k < 4; ++k) nt_store4(out + base + k * 256 + 1024, hi[k]);
}

extern "C" void kernel_launch(void* const* d_in, const int* in_sizes, int n_in,
                              void* d_out, int out_size, void* d_ws, size_t ws_size,
                              hipStream_t stream) {
    const f32x4* x = (const f32x4*)d_in[0];
    f32x4* out = (f32x4*)d_out;
    // total float4 per side: 4,194,304; 4 per thread -> 1,048,576 threads
    const int threads = 256;
    const int blocks = 1048576 / threads; // 4096
    groupsort_kernel<<<blocks, threads, 0, stream>>>(x, out);
}

// Round 3
// 221.829 us; speedup vs baseline: 1.0680x; 1.0680x over previous
//
#include <hip/hip_runtime.h>

// GroupSort: x[32,256,64,64] fp32. For each channel pair (2k, 2k+1):
//   d = x[2k] - x[2k+1]; r = relu(d); out[2k] = x[2k] - r  (= min)
//   out[2k+1] = x[2k+1] + r  (= max)
// Pure streaming op: 128 MiB in + 128 MiB out, zero reuse.
// Roofline: 268.4 MB @ 6.29 TB/s (m13 copy ceiling) = 42.6 us.
//
// Ladder:
//  R0: nt ld/st, 32B-interleaved pairs            -> kernel ~69 us
//  R1: nt ld/st, contiguous 1 KiB wave txns       -> kernel ~61 us (best)
//  R2: plain loads + 4 f4/side, flat 4096 blocks  -> 80 us, 2.5 TB/s, 61% occ
//      REGRESSION. Counters: all pipes idle -> issue/residency-limited,
//      not BW-limited. Reverting loads to nt; attacking load continuity.
//  R3 (this): persistent grid-stride (2048 blocks = 32 waves/CU resident,
//      zero inter-round bubbles) + depth-1 software pipeline (next iter's
//      loads issued before current iter's stores -> reads always in flight
//      across the DRAM read->write turnaround).
//
// Layout (R1's): plane = 1024 float4. u in [0, 2^21): pair = u>>9,
// within = u&511; thread covers base+{0,512} (even) and +{1024,1536} (odd).

typedef float f32x4 __attribute__((ext_vector_type(4)));

__device__ __forceinline__ f32x4 nt_load4(const f32x4* p) {
    return __builtin_nontemporal_load(p);
}
__device__ __forceinline__ void nt_store4(f32x4* p, f32x4 v) {
    __builtin_nontemporal_store(v, p);
}

__device__ __forceinline__ void pair_op(const f32x4 a, const f32x4 b,
                                        f32x4& lo, f32x4& hi) {
#pragma unroll
    for (int i = 0; i < 4; ++i) {
        float d = a[i] - b[i];
        float r = d > 0.0f ? d : 0.0f;
        lo[i] = a[i] - r;
        hi[i] = b[i] + r;
    }
}

__device__ __forceinline__ long base_of(long u) {
    const long pair   = u >> 9;
    const long within = u & 511;
    return pair * 2048 + within;
}

#define NTHREADS_TOTAL (2048L * 256L)   // 524288; 32 waves/CU resident
#define NITER 4                         // 524288 * 4 = 2^21 work units

__global__ __launch_bounds__(256, 8) void groupsort_kernel(
    const f32x4* __restrict__ x, f32x4* __restrict__ out) {
    const long t = (long)blockIdx.x * blockDim.x + threadIdx.x;

    long u = t;
    long base = base_of(u);
    f32x4 a0 = nt_load4(x + base);
    f32x4 a1 = nt_load4(x + base + 512);
    f32x4 b0 = nt_load4(x + base + 1024);
    f32x4 b1 = nt_load4(x + base + 1536);

#pragma unroll
    for (int it = 0; it < NITER; ++it) {
        long nbase = 0;
        f32x4 na0, na1, nb0, nb1;
        if (it < NITER - 1) {               // compile-time after unroll
            nbase = base_of(u + NTHREADS_TOTAL);
            na0 = nt_load4(x + nbase);
            na1 = nt_load4(x + nbase + 512);
            nb0 = nt_load4(x + nbase + 1024);
            nb1 = nt_load4(x + nbase + 1536);
        }

        f32x4 lo0, hi0, lo1, hi1;
        pair_op(a0, b0, lo0, hi0);
        pair_op(a1, b1, lo1, hi1);
        nt_store4(out + base,        lo0);
        nt_store4(out + base + 512,  lo1);
        nt_store4(out + base + 1024, hi0);
        nt_store4(out + base + 1536, hi1);

        if (it < NITER - 1) {
            base = nbase;
            a0 = na0; a1 = na1; b0 = nb0; b1 = nb1;
            u += NTHREADS_TOTAL;
        }
    }
}

extern "C" void kernel_launch(void* const* d_in, const int* in_sizes, int n_in,
                              void* d_out, int out_size, void* d_ws, size_t ws_size,
                              hipStream_t stream) {
    const f32x4* x = (const f32x4*)d_in[0];
    f32x4* out = (f32x4*)d_out;
    const int threads = 256;
    const int blocks = 2048;   // 8 blocks/CU x 4 waves = 32 waves/CU resident
    groupsort_kernel<<<blocks, threads, 0, stream>>>(x, out);
}